// Round 20
// baseline (220.973 us; speedup 1.0000x reference)
//
#include <hip/hip_runtime.h>

typedef short short8 __attribute__((ext_vector_type(8)));
typedef __bf16 bf16x8 __attribute__((ext_vector_type(8)));
typedef float f32x4 __attribute__((ext_vector_type(4)));

namespace {

constexpr int kNodeW = 320;   // NS + 3*NV
constexpr int kOutW  = 320;   // NS + 3*VOUT

// wsv frag indices (packed by pack_weights); 1 frag = 64 lanes * 16 B = 1 KB
constexpr int F_W1 = 0;    // kb*4 + nt (kb<2)
constexpr int F_W2 = 8;
constexpr int F_W3 = 16;   // kb*28 + seg*4 + nt (kb<2, seg<7)
constexpr int F_WS = 72;   // kb*12 + nt (kb<6)
constexpr int F_WP = 144;  // kb*4 + nt (kb<4)   Wv rows 0..127
constexpr int F_WQ = 160;  // kb*4 + nt (kb<2)   Wv rows 128..191
constexpr int F_WR = 168;  // kb*4 + nt (kb<2)   Wv rows 192..255
constexpr int NFRAG = 176;

// 4-wave block, 1 block/CU. LDS frag slots (1KB each):
//   [0,56)    W3 (all 7 segs, kb*28 + seg*4 + nt)
//   [56,128)  Ws (56 + kb*12 + nt)
//   [128,136) WQ, [136,144) WR, [144,152) WP kb0..1
// Arenas: 4 waves x 2KB at [152K, 160K).
constexpr int WAVES = 4;
constexpr int ARENA_OFF = 152 * 1024;
constexpr int SMEM_SZ = 160 * 1024;

constexpr float RS3 = 0.5773502691896258f;  // 1/sqrt(3)
constexpr float RS2 = 0.7071067811865476f;  // 1/sqrt(2)

__device__ __forceinline__ ushort f2b(float f) {
  __bf16 b = (__bf16)f;
  return __builtin_bit_cast(ushort, b);
}
__device__ __forceinline__ float fsig(float x) { return 1.0f / (1.0f + __expf(-x)); }
__device__ __forceinline__ float fsilu(float x) { return x / (1.0f + __expf(-x)); }
__device__ __forceinline__ f32x4 MFMA(short8 a, short8 b, f32x4 c) {
  return __builtin_amdgcn_mfma_f32_16x16x32_bf16(
      __builtin_bit_cast(bf16x8, a), __builtin_bit_cast(bf16x8, b), c, 0, 0, 0);
}

// arena slot: 16 rows x 64 bf16 (128 B rows), XOR swizzle on the row stride
__device__ __forceinline__ void cw16(char* ar, int row, int col, ushort v) {
  *(ushort*)(ar + ((row * 128 + col * 2) ^ ((row & 7) << 4))) = v;
}
__device__ __forceinline__ short8 cra(const char* ar, int row, int kb, int lg) {
  return *(const short8*)(ar + ((row * 128 + kb * 64 + lg * 16) ^ ((row & 7) << 4)));
}

// per-tile input state (kept in registers; ping-pong across the pipelined loop)
struct EState {
  int   geR[4];
  float e0v[4];
  float e1v[4][3];
  float sn[4][8];
  float vn[4][4][3];
  float4 esr[4];   // raw edge_scalars: {kb0 lo, kb0 hi, kb1 lo, kb1 hi}
};

// ---------------- B pack: f32 [K][N] -> bf16 frag layout in d_ws ----------------
__global__ void pack_weights(const float* __restrict__ W1, const float* __restrict__ W2,
                             const float* __restrict__ W3, const float* __restrict__ Ws,
                             const float* __restrict__ Wv, ushort* __restrict__ dst) {
  int f = blockIdx.x, lane = threadIdx.x;
  const float* src; int ldw, kbase, NT, local;
  if (f < 8)        { src = W1; ldw = 64;  kbase = 0;   NT = 4;  local = f; }
  else if (f < 16)  { src = W2; ldw = 64;  kbase = 0;   NT = 4;  local = f - 8; }
  else if (f < 72)  { src = W3; ldw = 448; kbase = 0;   NT = 28; local = f - 16; }
  else if (f < 144) { src = Ws; ldw = 192; kbase = 0;   NT = 12; local = f - 72; }
  else if (f < 160) { src = Wv; ldw = 64;  kbase = 0;   NT = 4;  local = f - 144; }
  else if (f < 168) { src = Wv; ldw = 64;  kbase = 128; NT = 4;  local = f - 160; }
  else              { src = Wv; ldw = 64;  kbase = 192; NT = 4;  local = f - 168; }
  int kb = local / NT, nt = local % NT;
  int k0  = kbase + kb * 32 + (lane >> 4) * 8;
  int col = nt * 16 + (lane & 15);
  ushort* o = dst + ((size_t)f * 64 + lane) * 8;
#pragma unroll
  for (int j = 0; j < 8; ++j) o[j] = f2b(src[(size_t)(k0 + j) * ldw + col]);
}

// ---- main: R17 structure + cross-tile software pipeline (register-neutral) ----
__global__ __launch_bounds__(256, 1) void fctp_main(
    const float* __restrict__ node, const float* __restrict__ eattr,
    const float* __restrict__ es, const float* __restrict__ b1,
    const float* __restrict__ b2, const float* __restrict__ offs,
    const float* __restrict__ bs, const float* __restrict__ g_s,
    const float* __restrict__ b_n, const float* __restrict__ g_v,
    const short8* __restrict__ wsv, float* __restrict__ out, int E) {
  __shared__ __align__(16) char smem[SMEM_SZ];
  const int lane = threadIdx.x & 63, wave = threadIdx.x >> 6;
  const int l15 = lane & 15, lg = lane >> 4;

  // ---- one-time: stage W3 + Ws + WQ + WR + WP(kb0,1) fragments (38/wave) ----
#pragma unroll
  for (int i = 0; i < 38; ++i) {
    int fl = wave * 38 + i;
    int fg = (fl < 56)  ? (F_W3 + fl)
           : (fl < 128) ? (F_WS + (fl - 56))
           : (fl < 136) ? (F_WQ + (fl - 128))
           : (fl < 144) ? (F_WR + (fl - 136))
                        : (F_WP + (fl - 144));
    *(short8*)(smem + fl * 1024 + lane * 16) = wsv[fg * 64 + lane];
  }
  __syncthreads();

  // ---- persistent W1/W2 B-fragments (16 x short8; MFMA-B -> AGPR-eligible) ----
  short8 w1f[8], w2f[8];
#pragma unroll
  for (int i = 0; i < 8; ++i) {
    w1f[i] = wsv[(F_W1 + i) * 64 + lane];
    w2f[i] = wsv[(F_W2 + i) * 64 + lane];
  }

  char* ar = smem + ARENA_OFF + wave * 2048;
  auto ldsB = [&](int f) -> short8 {
    return *(const short8*)(smem + f * 1024 + lane * 16);
  };

  const int ntiles = (E + 15) >> 4;
  const int stride = (int)gridDim.x * WAVES;
  int tl0 = (int)blockIdx.x * WAVES + wave;
  if (tl0 >= ntiles) return;

  // ---- state loaders (addresses clamped; safe for any tile index) ----
  auto loadHead = [&](int tl, EState& S) {  // geR, eattr, sn, raw es
    const int e0 = tl * 16;
    int geA = e0 + l15; if (geA >= E) geA = E - 1;
#pragma unroll
    for (int r = 0; r < 4; ++r) {
      int g = e0 + lg * 4 + r; if (g >= E) g = E - 1;
      S.geR[r] = g;
      float4 ea = *(const float4*)(eattr + (size_t)g * 4);
      S.e0v[r] = ea.x; S.e1v[r][0] = ea.y; S.e1v[r][1] = ea.z; S.e1v[r][2] = ea.w;
    }
#pragma unroll
    for (int r = 0; r < 4; ++r) {
      const float* ni = node + (size_t)S.geR[r] * kNodeW;
#pragma unroll
      for (int nt = 0; nt < 8; ++nt) S.sn[r][nt] = ni[nt * 16 + l15];
    }
#pragma unroll
    for (int kb = 0; kb < 2; ++kb) {
      const float* p = es + (size_t)geA * 64 + kb * 32 + lg * 8;
      S.esr[kb * 2]     = *(const float4*)p;
      S.esr[kb * 2 + 1] = *(const float4*)(p + 4);
    }
  };
  auto loadVn = [&](EState& S) {
#pragma unroll
    for (int r = 0; r < 4; ++r) {
      const float* ni = node + (size_t)S.geR[r] * kNodeW;
#pragma unroll
      for (int nt = 0; nt < 4; ++nt) {
        const float* vp = ni + 128 + 3 * (nt * 16 + l15);
        S.vn[r][nt][0] = vp[0]; S.vn[r][nt][1] = vp[1]; S.vn[r][nt][2] = vp[2];
      }
    }
  };

  // ---- one full tile; prefetches tile tl+stride into N at dead-register points
  auto body = [&](int tl, EState& C, EState& N) {
    const int e0 = tl * 16;

    // aes from raw es (loads completed during previous tile's tail)
    short8 aes[2];
#pragma unroll
    for (int kb = 0; kb < 2; ++kb) {
      float4 xa = C.esr[kb * 2], xb = C.esr[kb * 2 + 1];
      short8 a;
      a[0] = (short)f2b(xa.x); a[1] = (short)f2b(xa.y); a[2] = (short)f2b(xa.z); a[3] = (short)f2b(xa.w);
      a[4] = (short)f2b(xb.x); a[5] = (short)f2b(xb.y); a[6] = (short)f2b(xb.z); a[7] = (short)f2b(xb.w);
      aes[kb] = a;
    }

    // ---- MLP stage 1 (W1 from persistent regs) ----
    short8 ah[2];
    {
      f32x4 acc[4];
#pragma unroll
      for (int nt = 0; nt < 4; ++nt) { float bv = b1[nt * 16 + l15]; acc[nt] = (f32x4){bv, bv, bv, bv}; }
      __builtin_amdgcn_s_setprio(1);
#pragma unroll
      for (int kb = 0; kb < 2; ++kb)
#pragma unroll
        for (int nt = 0; nt < 4; ++nt)
          acc[nt] = MFMA(aes[kb], w1f[kb * 4 + nt], acc[nt]);
      __builtin_amdgcn_s_setprio(0);
#pragma unroll
      for (int nt = 0; nt < 4; ++nt)
#pragma unroll
        for (int r = 0; r < 4; ++r)
          cw16(ar, lg * 4 + r, nt * 16 + l15, f2b(fsilu(acc[nt][r])));
      ah[0] = cra(ar, l15, 0, lg);
      ah[1] = cra(ar, l15, 1, lg);
    }
    // ---- MLP stage 2 (W2 from persistent regs) ----
    {
      f32x4 acc[4];
#pragma unroll
      for (int nt = 0; nt < 4; ++nt) { float bv = b2[nt * 16 + l15]; acc[nt] = (f32x4){bv, bv, bv, bv}; }
      __builtin_amdgcn_s_setprio(1);
#pragma unroll
      for (int kb = 0; kb < 2; ++kb)
#pragma unroll
        for (int nt = 0; nt < 4; ++nt)
          acc[nt] = MFMA(ah[kb], w2f[kb * 4 + nt], acc[nt]);
      __builtin_amdgcn_s_setprio(0);
#pragma unroll
      for (int nt = 0; nt < 4; ++nt)
#pragma unroll
        for (int r = 0; r < 4; ++r)
          cw16(ar, lg * 4 + r, nt * 16 + l15, f2b(fsilu(acc[nt][r])));
      ah[0] = cra(ar, l15, 0, lg);
      ah[1] = cra(ar, l15, 1, lg);
    }

    // ---- phase helpers ----
    auto wseg = [&](int seg, f32x4 (&w)[4]) {   // W3 B-frags from LDS
#pragma unroll
      for (int nt = 0; nt < 4; ++nt) {
        float bv = offs[seg * 64 + nt * 16 + l15];
        w[nt] = (f32x4){bv, bv, bv, bv};
      }
      __builtin_amdgcn_s_setprio(1);
#pragma unroll
      for (int kb = 0; kb < 2; ++kb)
#pragma unroll
        for (int nt = 0; nt < 4; ++nt)
          w[nt] = MFMA(ah[kb], ldsB(kb * 28 + seg * 4 + nt), w[nt]);
      __builtin_amdgcn_s_setprio(0);
    };
    auto gemm12 = [&](int kb0, f32x4 (&sac)[12]) {  // Ws B-frags from LDS
      short8 a0 = cra(ar, l15, 0, lg), a1 = cra(ar, l15, 1, lg);
      __builtin_amdgcn_s_setprio(1);
#pragma unroll
      for (int nt = 0; nt < 12; ++nt)
        sac[nt] = MFMA(a0, ldsB(56 + kb0 * 12 + nt), sac[nt]);
#pragma unroll
      for (int nt = 0; nt < 12; ++nt)
        sac[nt] = MFMA(a1, ldsB(56 + (kb0 + 1) * 12 + nt), sac[nt]);
      __builtin_amdgcn_s_setprio(0);
    };
    auto gemm4g = [&](int fb0, int fb1, f32x4 (&ac)[4]) {  // WP kb2,3 from global
      short8 a0 = cra(ar, l15, 0, lg), a1 = cra(ar, l15, 1, lg);
      __builtin_amdgcn_s_setprio(1);
#pragma unroll
      for (int nt = 0; nt < 4; ++nt) ac[nt] = MFMA(a0, wsv[(fb0 + nt) * 64 + lane], ac[nt]);
#pragma unroll
      for (int nt = 0; nt < 4; ++nt) ac[nt] = MFMA(a1, wsv[(fb1 + nt) * 64 + lane], ac[nt]);
      __builtin_amdgcn_s_setprio(0);
    };
    auto gemm4L = [&](int s0, f32x4 (&ac)[4]) {  // WQ/WR/WP(kb0,1) from LDS
      short8 a0 = cra(ar, l15, 0, lg), a1 = cra(ar, l15, 1, lg);
      __builtin_amdgcn_s_setprio(1);
#pragma unroll
      for (int nt = 0; nt < 4; ++nt) ac[nt] = MFMA(a0, ldsB(s0 + nt), ac[nt]);
#pragma unroll
      for (int nt = 0; nt < 4; ++nt) ac[nt] = MFMA(a1, ldsB(s0 + 4 + nt), ac[nt]);
      __builtin_amdgcn_s_setprio(0);
    };
    auto tpS = [&](const f32x4 (&w)[4], int nb, bool mulE0) {
#pragma unroll
      for (int nt = 0; nt < 4; ++nt)
#pragma unroll
        for (int r = 0; r < 4; ++r) {
          float v = w[nt][r] * C.sn[r][nb + nt];
          if (mulE0) v *= C.e0v[r];
          cw16(ar, lg * 4 + r, nt * 16 + l15, f2b(v));
        }
    };
    auto tpD = [&](const f32x4 (&w)[4]) {
#pragma unroll
      for (int nt = 0; nt < 4; ++nt)
#pragma unroll
        for (int r = 0; r < 4; ++r) {
          float dot = C.vn[r][nt][0] * C.e1v[r][0] + C.vn[r][nt][1] * C.e1v[r][1] +
                      C.vn[r][nt][2] * C.e1v[r][2];
          cw16(ar, lg * 4 + r, nt * 16 + l15, f2b(w[nt][r] * dot * RS3));
        }
    };
    auto tpQ = [&](const f32x4 (&w)[4], int c) {  // e0 folded in
#pragma unroll
      for (int nt = 0; nt < 4; ++nt)
#pragma unroll
        for (int r = 0; r < 4; ++r)
          cw16(ar, lg * 4 + r, nt * 16 + l15,
               f2b(C.e0v[r] * w[nt][r] * C.vn[r][nt][c]));
    };
    auto tpR = [&](const f32x4 (&w)[4], int c) {
      const int i1 = (c + 1) % 3, i2 = (c + 2) % 3;
#pragma unroll
      for (int nt = 0; nt < 4; ++nt)
#pragma unroll
        for (int r = 0; r < 4; ++r) {
          float cr = C.vn[r][nt][i1] * C.e1v[r][i2] - C.vn[r][nt][i2] * C.e1v[r][i1];
          cw16(ar, lg * 4 + r, nt * 16 + l15, f2b(w[nt][r] * cr * RS2));
        }
    };

    // ---- s phase ----
    f32x4 wacc[4];
    f32x4 sacc[12];
#pragma unroll
    for (int nt = 0; nt < 12; ++nt) { float bv = bs[nt * 16 + l15]; sacc[nt] = (f32x4){bv, bv, bv, bv}; }
    wseg(0, wacc); tpS(wacc, 0, true);  gemm12(0, sacc);
    wseg(1, wacc); tpS(wacc, 4, true);  gemm12(2, sacc);
    wseg(5, wacc); tpD(wacc);           gemm12(4, sacc);

    // ---- layernorm + silu / gate + scalar store ----
    float gate[4][4];
    {
      float gsv[12], bnv[12];
#pragma unroll
      for (int nt = 0; nt < 12; ++nt) { gsv[nt] = g_s[nt * 16 + l15]; bnv[nt] = b_n[nt * 16 + l15]; }
#pragma unroll
      for (int r = 0; r < 4; ++r) {
        float sx = 0.f, sxx = 0.f;
#pragma unroll
        for (int nt = 0; nt < 12; ++nt) { float v = sacc[nt][r]; sx += v; sxx += v * v; }
#pragma unroll
        for (int m = 8; m >= 1; m >>= 1) { sx += __shfl_xor(sx, m); sxx += __shfl_xor(sxx, m); }
        float mean = sx * (1.0f / 192.0f);
        float var  = sxx * (1.0f / 192.0f) - mean * mean;
        float rstd = rsqrtf(var + 1e-5f);
        int geu = e0 + lg * 4 + r;
        bool valid = geu < E;
        float* ob = out + (size_t)(valid ? geu : 0) * kOutW;
#pragma unroll
        for (int nt = 0; nt < 12; ++nt) {
          float s_n = gsv[nt] * (sacc[nt][r] - mean) * rstd + bnv[nt];
          if (nt < 8) { if (valid) ob[nt * 16 + l15] = fsilu(s_n); }
          else gate[r][nt - 8] = fsig(s_n);
        }
      }
    }

    // ---- p phase (last use of C.sn) ----
    f32x4 pacc[4];
#pragma unroll
    for (int nt = 0; nt < 4; ++nt) pacc[nt] = (f32x4){0.f, 0.f, 0.f, 0.f};
    wseg(2, wacc); tpS(wacc, 0, false); gemm4L(144, pacc);
    wseg(3, wacc); tpS(wacc, 4, false); gemm4g(F_WP + 8, F_WP + 12, pacc);

    // ==== PREFETCH A: next tile's geR/eattr/sn/es (C.sn now dead) ====
    loadHead(tl + stride, N);

    // ---- q phase ----
    f32x4 vl[3][4];
    wseg(4, wacc);
#pragma unroll
    for (int c = 0; c < 3; ++c) {
#pragma unroll
      for (int nt = 0; nt < 4; ++nt)
#pragma unroll
        for (int r = 0; r < 4; ++r)
          vl[c][nt][r] = pacc[nt][r] * C.e1v[r][c];
      tpQ(wacc, c);
      gemm4L(128, vl[c]);
    }
    // ---- t phase (last use of C.vn) ----
    wseg(6, wacc);
#pragma unroll
    for (int c = 0; c < 3; ++c) {
      tpR(wacc, c);
      gemm4L(136, vl[c]);
    }

    // ==== PREFETCH B: next tile's vn (C.vn now dead) ====
    loadVn(N);

    // ---- RMS norm + gate + vector store ----
    {
      float gvv[4];
#pragma unroll
      for (int nt = 0; nt < 4; ++nt) gvv[nt] = g_v[nt * 16 + l15];
#pragma unroll
      for (int r = 0; r < 4; ++r) {
        float vsq = 0.f;
#pragma unroll
        for (int c = 0; c < 3; ++c)
#pragma unroll
          for (int nt = 0; nt < 4; ++nt) { float v = vl[c][nt][r]; vsq += v * v; }
#pragma unroll
        for (int m = 8; m >= 1; m >>= 1) vsq += __shfl_xor(vsq, m);
        float vnrm = rsqrtf(vsq * (1.0f / 64.0f) + 1e-5f);
        int geu = e0 + lg * 4 + r;
        if (geu < E) {
          float* ob = out + (size_t)geu * kOutW + 128;
#pragma unroll
          for (int nt = 0; nt < 4; ++nt) {
            float m3 = gvv[nt] * vnrm * gate[r][nt];
            int o3 = (nt * 16 + l15) * 3;
            ob[o3 + 0] = m3 * vl[0][nt][r];
            ob[o3 + 1] = m3 * vl[1][nt][r];
            ob[o3 + 2] = m3 * vl[2][nt][r];
          }
        }
      }
    }
  };

  // ---- pipelined loop: 2x unrolled ping-pong (no state copies) ----
  EState S0, S1;
  loadHead(tl0, S0);
  loadVn(S0);
  int tl = tl0;
  for (;;) {
    body(tl, S0, S1);
    tl += stride; if (tl >= ntiles) break;
    body(tl, S1, S0);
    tl += stride; if (tl >= ntiles) break;
  }
}

}  // namespace

extern "C" void kernel_launch(void* const* d_in, const int* in_sizes, int n_in,
                              void* d_out, int out_size, void* d_ws, size_t ws_size,
                              hipStream_t stream) {
  const float* node_input   = (const float*)d_in[0];
  const float* edge_attr    = (const float*)d_in[1];
  const float* edge_scalars = (const float*)d_in[2];
  const float* W1 = (const float*)d_in[3];
  const float* b1 = (const float*)d_in[4];
  const float* W2 = (const float*)d_in[5];
  const float* b2 = (const float*)d_in[6];
  const float* W3 = (const float*)d_in[7];
  const float* offset = (const float*)d_in[8];
  const float* Ws = (const float*)d_in[9];
  const float* bs = (const float*)d_in[10];
  const float* Wv = (const float*)d_in[11];
  const float* g_s = (const float*)d_in[12];
  const float* b_n = (const float*)d_in[13];
  const float* g_v = (const float*)d_in[14];
  float* out = (float*)d_out;

  const int E = in_sizes[0] / kNodeW;

  pack_weights<<<NFRAG, 64, 0, stream>>>(W1, W2, W3, Ws, Wv, (ushort*)d_ws);

  const int ntiles = (E + 15) / 16;
  int blocks = (ntiles + WAVES - 1) / WAVES;
  if (blocks > 256) blocks = 256;  // 1 block/CU resident; grid-stride the rest
  fctp_main<<<blocks, WAVES * 64, 0, stream>>>(
      node_input, edge_attr, edge_scalars, b1, b2, offset, bs, g_s, b_n, g_v,
      (const short8*)d_ws, out, E);
}

// Round 21
// 179.787 us; speedup vs baseline: 1.2291x; 1.2291x over previous
//
#include <hip/hip_runtime.h>

typedef short short8 __attribute__((ext_vector_type(8)));
typedef __bf16 bf16x8 __attribute__((ext_vector_type(8)));
typedef float f32x4 __attribute__((ext_vector_type(4)));

namespace {

constexpr int kNodeW = 320;   // NS + 3*NV
constexpr int kOutW  = 320;   // NS + 3*VOUT

// wsv frag indices (packed by pack_weights); 1 frag = 64 lanes * 16 B = 1 KB
constexpr int F_W1 = 0;    // kb*4 + nt (kb<2)
constexpr int F_W2 = 8;
constexpr int F_W3 = 16;   // kb*28 + seg*4 + nt (kb<2, seg<7)
constexpr int F_WS = 72;   // kb*12 + nt (kb<6)
constexpr int F_WP = 144;  // kb*4 + nt (kb<4)   Wv rows 0..127
constexpr int F_WQ = 160;  // kb*4 + nt (kb<2)   Wv rows 128..191
constexpr int F_WR = 168;  // kb*4 + nt (kb<2)   Wv rows 192..255
constexpr int NFRAG = 176;

// 4-wave block, 1 block/CU. LDS frag slots (1KB each):
//   [0,56)    W3 (all 7 segs, kb*28 + seg*4 + nt)
//   [56,128)  Ws (56 + kb*12 + nt)
//   [128,136) WQ, [136,144) WR, [144,152) WP kb0..1
// Arenas: 4 waves x 2KB at [152K, 160K).
constexpr int WAVES = 4;
constexpr int ARENA_OFF = 152 * 1024;
constexpr int SMEM_SZ = 160 * 1024;

constexpr float RS3 = 0.5773502691896258f;  // 1/sqrt(3)
constexpr float RS2 = 0.7071067811865476f;  // 1/sqrt(2)

__device__ __forceinline__ ushort f2b(float f) {
  __bf16 b = (__bf16)f;
  return __builtin_bit_cast(ushort, b);
}
__device__ __forceinline__ float fsig(float x) { return 1.0f / (1.0f + __expf(-x)); }
__device__ __forceinline__ float fsilu(float x) { return x / (1.0f + __expf(-x)); }
__device__ __forceinline__ f32x4 MFMA(short8 a, short8 b, f32x4 c) {
  return __builtin_amdgcn_mfma_f32_16x16x32_bf16(
      __builtin_bit_cast(bf16x8, a), __builtin_bit_cast(bf16x8, b), c, 0, 0, 0);
}

// arena slot: 16 rows x 64 bf16 (128 B rows), XOR swizzle on the row stride
__device__ __forceinline__ void cw16(char* ar, int row, int col, ushort v) {
  *(ushort*)(ar + ((row * 128 + col * 2) ^ ((row & 7) << 4))) = v;
}
__device__ __forceinline__ short8 cra(const char* ar, int row, int kb, int lg) {
  return *(const short8*)(ar + ((row * 128 + kb * 64 + lg * 16) ^ ((row & 7) << 4)));
}

// ---------------- B pack: f32 [K][N] -> bf16 frag layout in d_ws ----------------
__global__ void pack_weights(const float* __restrict__ W1, const float* __restrict__ W2,
                             const float* __restrict__ W3, const float* __restrict__ Ws,
                             const float* __restrict__ Wv, ushort* __restrict__ dst) {
  int f = blockIdx.x, lane = threadIdx.x;
  const float* src; int ldw, kbase, NT, local;
  if (f < 8)        { src = W1; ldw = 64;  kbase = 0;   NT = 4;  local = f; }
  else if (f < 16)  { src = W2; ldw = 64;  kbase = 0;   NT = 4;  local = f - 8; }
  else if (f < 72)  { src = W3; ldw = 448; kbase = 0;   NT = 28; local = f - 16; }
  else if (f < 144) { src = Ws; ldw = 192; kbase = 0;   NT = 12; local = f - 72; }
  else if (f < 160) { src = Wv; ldw = 64;  kbase = 0;   NT = 4;  local = f - 144; }
  else if (f < 168) { src = Wv; ldw = 64;  kbase = 128; NT = 4;  local = f - 160; }
  else              { src = Wv; ldw = 64;  kbase = 192; NT = 4;  local = f - 168; }
  int kb = local / NT, nt = local % NT;
  int k0  = kbase + kb * 32 + (lane >> 4) * 8;
  int col = nt * 16 + (lane & 15);
  ushort* o = dst + ((size_t)f * 64 + lane) * 8;
#pragma unroll
  for (int j = 0; j < 8; ++j) o[j] = f2b(src[(size_t)(k0 + j) * ldw + col]);
}

// ---- main: 4 waves (1/SIMD -> 512-reg budget), persistent W1/W2 + setprio -----
__global__ __launch_bounds__(256, 1) void fctp_main(
    const float* __restrict__ node, const float* __restrict__ eattr,
    const float* __restrict__ es, const float* __restrict__ b1,
    const float* __restrict__ b2, const float* __restrict__ offs,
    const float* __restrict__ bs, const float* __restrict__ g_s,
    const float* __restrict__ b_n, const float* __restrict__ g_v,
    const short8* __restrict__ wsv, float* __restrict__ out, int E) {
  __shared__ __align__(16) char smem[SMEM_SZ];
  const int lane = threadIdx.x & 63, wave = threadIdx.x >> 6;
  const int l15 = lane & 15, lg = lane >> 4;

  // ---- one-time: stage W3 + Ws + WQ + WR + WP(kb0,1) fragments (38/wave) ----
#pragma unroll
  for (int i = 0; i < 38; ++i) {
    int fl = wave * 38 + i;
    int fg = (fl < 56)  ? (F_W3 + fl)
           : (fl < 128) ? (F_WS + (fl - 56))
           : (fl < 136) ? (F_WQ + (fl - 128))
           : (fl < 144) ? (F_WR + (fl - 136))
                        : (F_WP + (fl - 144));
    *(short8*)(smem + fl * 1024 + lane * 16) = wsv[fg * 64 + lane];
  }
  __syncthreads();

  // ---- persistent W1/W2 B-fragments (16 x short8; MFMA-B -> AGPR-eligible) ----
  short8 w1f[8], w2f[8];
#pragma unroll
  for (int i = 0; i < 8; ++i) {
    w1f[i] = wsv[(F_W1 + i) * 64 + lane];
    w2f[i] = wsv[(F_W2 + i) * 64 + lane];
  }

  char* ar = smem + ARENA_OFF + wave * 2048;
  auto ldsB = [&](int f) -> short8 {
    return *(const short8*)(smem + f * 1024 + lane * 16);
  };

  const int ntiles = (E + 15) >> 4;
  for (int tile = (int)blockIdx.x * WAVES + wave; tile < ntiles;
       tile += (int)gridDim.x * WAVES) {
    const int e0 = tile * 16;
    int geA = e0 + l15; if (geA >= E) geA = E - 1;
    int geR[4];
    float e0v[4], e1v[4][3];
#pragma unroll
    for (int r = 0; r < 4; ++r) {
      int g = e0 + lg * 4 + r; if (g >= E) g = E - 1;
      geR[r] = g;
      float4 ea = *(const float4*)(eattr + (size_t)g * 4);
      e0v[r] = ea.x; e1v[r][0] = ea.y; e1v[r][1] = ea.z; e1v[r][2] = ea.w;
    }

    // node preloads (single pass; lane's C-layout rows)
    float sn[4][8];
    float vn[4][4][3];
#pragma unroll
    for (int r = 0; r < 4; ++r) {
      const float* ni = node + (size_t)geR[r] * kNodeW;
#pragma unroll
      for (int nt = 0; nt < 8; ++nt) sn[r][nt] = ni[nt * 16 + l15];
#pragma unroll
      for (int nt = 0; nt < 4; ++nt) {
        const float* vp = ni + 128 + 3 * (nt * 16 + l15);
        vn[r][nt][0] = vp[0]; vn[r][nt][1] = vp[1]; vn[r][nt][2] = vp[2];
      }
    }

    // es A-fragments
    short8 aes[2];
#pragma unroll
    for (int kb = 0; kb < 2; ++kb) {
      const float* p = es + (size_t)geA * 64 + kb * 32 + lg * 8;
      float4 xa = *(const float4*)p, xb = *(const float4*)(p + 4);
      short8 a;
      a[0] = (short)f2b(xa.x); a[1] = (short)f2b(xa.y); a[2] = (short)f2b(xa.z); a[3] = (short)f2b(xa.w);
      a[4] = (short)f2b(xb.x); a[5] = (short)f2b(xb.y); a[6] = (short)f2b(xb.z); a[7] = (short)f2b(xb.w);
      aes[kb] = a;
    }

    // ---- MLP stage 1 (W1 from persistent regs) ----
    short8 ah[2];
    {
      f32x4 acc[4];
#pragma unroll
      for (int nt = 0; nt < 4; ++nt) { float bv = b1[nt * 16 + l15]; acc[nt] = (f32x4){bv, bv, bv, bv}; }
      __builtin_amdgcn_s_setprio(1);
#pragma unroll
      for (int kb = 0; kb < 2; ++kb)
#pragma unroll
        for (int nt = 0; nt < 4; ++nt)
          acc[nt] = MFMA(aes[kb], w1f[kb * 4 + nt], acc[nt]);
      __builtin_amdgcn_s_setprio(0);
#pragma unroll
      for (int nt = 0; nt < 4; ++nt)
#pragma unroll
        for (int r = 0; r < 4; ++r)
          cw16(ar, lg * 4 + r, nt * 16 + l15, f2b(fsilu(acc[nt][r])));
      ah[0] = cra(ar, l15, 0, lg);
      ah[1] = cra(ar, l15, 1, lg);
    }
    // ---- MLP stage 2 (W2 from persistent regs) ----
    {
      f32x4 acc[4];
#pragma unroll
      for (int nt = 0; nt < 4; ++nt) { float bv = b2[nt * 16 + l15]; acc[nt] = (f32x4){bv, bv, bv, bv}; }
      __builtin_amdgcn_s_setprio(1);
#pragma unroll
      for (int kb = 0; kb < 2; ++kb)
#pragma unroll
        for (int nt = 0; nt < 4; ++nt)
          acc[nt] = MFMA(ah[kb], w2f[kb * 4 + nt], acc[nt]);
      __builtin_amdgcn_s_setprio(0);
#pragma unroll
      for (int nt = 0; nt < 4; ++nt)
#pragma unroll
        for (int r = 0; r < 4; ++r)
          cw16(ar, lg * 4 + r, nt * 16 + l15, f2b(fsilu(acc[nt][r])));
      ah[0] = cra(ar, l15, 0, lg);
      ah[1] = cra(ar, l15, 1, lg);
    }

    // ---- helpers ----
    auto wseg = [&](int seg, f32x4 (&w)[4]) {   // W3 B-frags from LDS
#pragma unroll
      for (int nt = 0; nt < 4; ++nt) {
        float bv = offs[seg * 64 + nt * 16 + l15];
        w[nt] = (f32x4){bv, bv, bv, bv};
      }
      __builtin_amdgcn_s_setprio(1);
#pragma unroll
      for (int kb = 0; kb < 2; ++kb)
#pragma unroll
        for (int nt = 0; nt < 4; ++nt)
          w[nt] = MFMA(ah[kb], ldsB(kb * 28 + seg * 4 + nt), w[nt]);
      __builtin_amdgcn_s_setprio(0);
    };
    auto gemm12 = [&](int kb0, f32x4 (&sac)[12]) {  // Ws B-frags from LDS
      short8 a0 = cra(ar, l15, 0, lg), a1 = cra(ar, l15, 1, lg);
      __builtin_amdgcn_s_setprio(1);
#pragma unroll
      for (int nt = 0; nt < 12; ++nt)
        sac[nt] = MFMA(a0, ldsB(56 + kb0 * 12 + nt), sac[nt]);
#pragma unroll
      for (int nt = 0; nt < 12; ++nt)
        sac[nt] = MFMA(a1, ldsB(56 + (kb0 + 1) * 12 + nt), sac[nt]);
      __builtin_amdgcn_s_setprio(0);
    };
    auto gemm4g = [&](int fb0, int fb1, f32x4 (&ac)[4]) {  // WP kb2,3 from global
      short8 a0 = cra(ar, l15, 0, lg), a1 = cra(ar, l15, 1, lg);
      __builtin_amdgcn_s_setprio(1);
#pragma unroll
      for (int nt = 0; nt < 4; ++nt) ac[nt] = MFMA(a0, wsv[(fb0 + nt) * 64 + lane], ac[nt]);
#pragma unroll
      for (int nt = 0; nt < 4; ++nt) ac[nt] = MFMA(a1, wsv[(fb1 + nt) * 64 + lane], ac[nt]);
      __builtin_amdgcn_s_setprio(0);
    };
    auto gemm4L = [&](int s0, f32x4 (&ac)[4]) {  // WQ/WR/WP(kb0,1) from LDS
      short8 a0 = cra(ar, l15, 0, lg), a1 = cra(ar, l15, 1, lg);
      __builtin_amdgcn_s_setprio(1);
#pragma unroll
      for (int nt = 0; nt < 4; ++nt) ac[nt] = MFMA(a0, ldsB(s0 + nt), ac[nt]);
#pragma unroll
      for (int nt = 0; nt < 4; ++nt) ac[nt] = MFMA(a1, ldsB(s0 + 4 + nt), ac[nt]);
      __builtin_amdgcn_s_setprio(0);
    };
    auto tpS = [&](const f32x4 (&w)[4], int nb, bool mulE0) {
#pragma unroll
      for (int nt = 0; nt < 4; ++nt)
#pragma unroll
        for (int r = 0; r < 4; ++r) {
          float v = w[nt][r] * sn[r][nb + nt];
          if (mulE0) v *= e0v[r];
          cw16(ar, lg * 4 + r, nt * 16 + l15, f2b(v));
        }
    };
    auto tpD = [&](const f32x4 (&w)[4]) {
#pragma unroll
      for (int nt = 0; nt < 4; ++nt)
#pragma unroll
        for (int r = 0; r < 4; ++r) {
          float dot = vn[r][nt][0] * e1v[r][0] + vn[r][nt][1] * e1v[r][1] +
                      vn[r][nt][2] * e1v[r][2];
          cw16(ar, lg * 4 + r, nt * 16 + l15, f2b(w[nt][r] * dot * RS3));
        }
    };
    auto tpQ = [&](const f32x4 (&w)[4], int c) {  // e0 folded in (R9-verified)
#pragma unroll
      for (int nt = 0; nt < 4; ++nt)
#pragma unroll
        for (int r = 0; r < 4; ++r)
          cw16(ar, lg * 4 + r, nt * 16 + l15,
               f2b(e0v[r] * w[nt][r] * vn[r][nt][c]));
    };
    auto tpR = [&](const f32x4 (&w)[4], int c) {
      const int i1 = (c + 1) % 3, i2 = (c + 2) % 3;
#pragma unroll
      for (int nt = 0; nt < 4; ++nt)
#pragma unroll
        for (int r = 0; r < 4; ++r) {
          float cr = vn[r][nt][i1] * e1v[r][i2] - vn[r][nt][i2] * e1v[r][i1];
          cw16(ar, lg * 4 + r, nt * 16 + l15, f2b(w[nt][r] * cr * RS2));
        }
    };

    // ---- s phase: sacc = scal @ Ws + bs (partial-K through arena) ----
    f32x4 wacc[4];
    f32x4 sacc[12];
#pragma unroll
    for (int nt = 0; nt < 12; ++nt) { float bv = bs[nt * 16 + l15]; sacc[nt] = (f32x4){bv, bv, bv, bv}; }
    wseg(0, wacc); tpS(wacc, 0, true);  gemm12(0, sacc);
    wseg(1, wacc); tpS(wacc, 4, true);  gemm12(2, sacc);
    wseg(5, wacc); tpD(wacc);           gemm12(4, sacc);

    // ---- layernorm + silu / gate + scalar store ----
    float gate[4][4];
    {
      float gsv[12], bnv[12];
#pragma unroll
      for (int nt = 0; nt < 12; ++nt) { gsv[nt] = g_s[nt * 16 + l15]; bnv[nt] = b_n[nt * 16 + l15]; }
#pragma unroll
      for (int r = 0; r < 4; ++r) {
        float sx = 0.f, sxx = 0.f;
#pragma unroll
        for (int nt = 0; nt < 12; ++nt) { float v = sacc[nt][r]; sx += v; sxx += v * v; }
#pragma unroll
        for (int m = 8; m >= 1; m >>= 1) { sx += __shfl_xor(sx, m); sxx += __shfl_xor(sxx, m); }
        float mean = sx * (1.0f / 192.0f);
        float var  = sxx * (1.0f / 192.0f) - mean * mean;
        float rstd = rsqrtf(var + 1e-5f);
        int geu = e0 + lg * 4 + r;
        bool valid = geu < E;
        float* ob = out + (size_t)(valid ? geu : 0) * kOutW;
#pragma unroll
        for (int nt = 0; nt < 12; ++nt) {
          float s_n = gsv[nt] * (sacc[nt][r] - mean) * rstd + bnv[nt];
          if (nt < 8) { if (valid) ob[nt * 16 + l15] = fsilu(s_n); }
          else gate[r][nt - 8] = fsig(s_n);
        }
      }
    }

    // ---- v phase ----
    f32x4 pacc[4];
#pragma unroll
    for (int nt = 0; nt < 4; ++nt) pacc[nt] = (f32x4){0.f, 0.f, 0.f, 0.f};
    wseg(2, wacc); tpS(wacc, 0, false); gemm4L(144, pacc);                 // WP kb0,1 (LDS)
    wseg(3, wacc); tpS(wacc, 4, false); gemm4g(F_WP + 8, F_WP + 12, pacc); // WP kb2,3 (L2)

    f32x4 vl[3][4];
    wseg(4, wacc);
#pragma unroll
    for (int c = 0; c < 3; ++c) {
      // init vl[c] from pacc, then q-GEMM (e0 folded into TP) accumulates in
#pragma unroll
      for (int nt = 0; nt < 4; ++nt)
#pragma unroll
        for (int r = 0; r < 4; ++r)
          vl[c][nt][r] = pacc[nt][r] * e1v[r][c];
      tpQ(wacc, c);
      gemm4L(128, vl[c]);
    }
    wseg(6, wacc);
#pragma unroll
    for (int c = 0; c < 3; ++c) {
      tpR(wacc, c);
      gemm4L(136, vl[c]);
    }

    // ---- RMS norm + gate + vector store ----
    {
      float gvv[4];
#pragma unroll
      for (int nt = 0; nt < 4; ++nt) gvv[nt] = g_v[nt * 16 + l15];
#pragma unroll
      for (int r = 0; r < 4; ++r) {
        float vsq = 0.f;
#pragma unroll
        for (int c = 0; c < 3; ++c)
#pragma unroll
          for (int nt = 0; nt < 4; ++nt) { float v = vl[c][nt][r]; vsq += v * v; }
#pragma unroll
        for (int m = 8; m >= 1; m >>= 1) vsq += __shfl_xor(vsq, m);
        float vnrm = rsqrtf(vsq * (1.0f / 64.0f) + 1e-5f);
        int geu = e0 + lg * 4 + r;
        if (geu < E) {
          float* ob = out + (size_t)geu * kOutW + 128;
#pragma unroll
          for (int nt = 0; nt < 4; ++nt) {
            float m3 = gvv[nt] * vnrm * gate[r][nt];
            int o3 = (nt * 16 + l15) * 3;
            ob[o3 + 0] = m3 * vl[0][nt][r];
            ob[o3 + 1] = m3 * vl[1][nt][r];
            ob[o3 + 2] = m3 * vl[2][nt][r];
          }
        }
      }
    }
  }
}

}  // namespace

extern "C" void kernel_launch(void* const* d_in, const int* in_sizes, int n_in,
                              void* d_out, int out_size, void* d_ws, size_t ws_size,
                              hipStream_t stream) {
  const float* node_input   = (const float*)d_in[0];
  const float* edge_attr    = (const float*)d_in[1];
  const float* edge_scalars = (const float*)d_in[2];
  const float* W1 = (const float*)d_in[3];
  const float* b1 = (const float*)d_in[4];
  const float* W2 = (const float*)d_in[5];
  const float* b2 = (const float*)d_in[6];
  const float* W3 = (const float*)d_in[7];
  const float* offset = (const float*)d_in[8];
  const float* Ws = (const float*)d_in[9];
  const float* bs = (const float*)d_in[10];
  const float* Wv = (const float*)d_in[11];
  const float* g_s = (const float*)d_in[12];
  const float* b_n = (const float*)d_in[13];
  const float* g_v = (const float*)d_in[14];
  float* out = (float*)d_out;

  const int E = in_sizes[0] / kNodeW;

  pack_weights<<<NFRAG, 64, 0, stream>>>(W1, W2, W3, Ws, Wv, (ushort*)d_ws);

  const int ntiles = (E + 15) / 16;
  int blocks = (ntiles + WAVES - 1) / WAVES;
  if (blocks > 256) blocks = 256;  // 1 block/CU resident; grid-stride the rest
  fctp_main<<<blocks, WAVES * 64, 0, stream>>>(
      node_input, edge_attr, edge_scalars, b1, b2, offset, bs, g_s, b_n, g_v,
      (const short8*)d_ws, out, E);
}